// Round 14
// baseline (101.839 us; speedup 1.0000x reference)
//
#include <hip/hip_runtime.h>
#include <math.h>

#define NL 28
#define H 1024
#define W 1024
#define HW (H * W)
#define BROW 1152         // padded row: 64 guard | 1024 data | 64 guard
#define GUARD 64
#define NBUF 3            // x buffers (depth-2 prefetch)
#define NPASS 9           // 9 x 128 px passes cover Wp <= 1152

// 8B vector, 4B-alignment-safe -> ds_read2_b32.
typedef float f2 __attribute__((ext_vector_type(2), aligned(4)));

typedef __attribute__((address_space(1))) const void GV;
typedef __attribute__((address_space(3))) void LV;
__device__ __forceinline__ void gl_lds16(const float* g, float* l) {
    __builtin_amdgcn_global_load_lds((GV*)g, (LV*)l, 16, 0, 0);
}

// out[Y,X] = sum_l mask[Y-dy_l, X-dx_l] * x[l, Y-dy_l, X-dx_l]
// v14: ONE WAVE per block owns one full output row and all 28 bands.
// Zero barriers, zero partial exchange (v12's only remaining overheads):
// the wave stages mask rows Y/Y-1 + x rows through a private 3-buffer
// counted-vmcnt pipeline (v12's proven schedule) and stores acc directly.
// 22.5 KB LDS -> 7 independent block timelines per CU hide each other's
// prologue/drain phases. x traffic exactly 1x (112 MB).
__global__ __launch_bounds__(64)
void cassi_v14(const float* __restrict__ x, const float* __restrict__ mask,
               const float* __restrict__ phi_deg, const float* __restrict__ s_nom,
               float* __restrict__ out, int out_size)
{
    __shared__ float lds[(NBUF + 2) * BROW];  // 3 x-bufs + 2 mask rows = 22.5 KB

    const int lane = threadIdx.x;  // 64-thread block = 1 wave

    // ---- offsets: lane-parallel float math (validated r1-r13) ----
    float phi = phi_deg[0] * 0.017453292519943295f;
    float c = cosf(phi), sn = sinf(phi);
    float s = (lane < NL) ? s_nom[lane] : 0.f;
    float dxv = s * c, dyv = s * sn;
    float dxm = (lane < NL) ? dxv : 3.0e38f;
    float dym = (lane < NL) ? dyv : 3.0e38f;
    for (int d = 1; d < 64; d <<= 1) {
        dxm = fminf(dxm, __shfl_xor(dxm, d, 64));
        dym = fminf(dym, __shfl_xor(dym, d, 64));
    }
    int dxi = (lane < NL) ? (int)rintf(dxv - dxm) : 0;
    int dyi = (lane < NL) ? (int)rintf(dyv - dym) : 0;
    int dxmax = dxi, dymax = dyi;
    for (int d = 1; d < 64; d <<= 1) {
        dxmax = max(dxmax, __shfl_xor(dxmax, d, 64));
        dymax = max(dymax, __shfl_xor(dymax, d, 64));
    }
    const int Wp = W + dxmax;
    const int Hp = out_size / Wp;

    if (!(dymax <= 1 && dxmax <= GUARD)) {
        // Self-contained checked fallback (never taken for bench geometry).
        for (int i = blockIdx.x * 64 + lane; i < out_size; i += gridDim.x * 64) {
            int Yk = i / Wp, Xk = i - Yk * Wp;
            float a = 0.f;
            for (int l = 0; l < NL; ++l) {
                float sl = s_nom[l];
                int dx = (int)rintf(sl * c - dxm);
                int dy = (int)rintf(sl * sn - dym);
                int h = Yk - dy, w = Xk - dx;
                if ((unsigned)h < (unsigned)H && (unsigned)w < (unsigned)W) {
                    int p = h * W + w;
                    a = fmaf(mask[p], x[(size_t)l * HW + p], a);
                }
            }
            out[i] = a;
        }
        return;
    }

    const int Y = blockIdx.x;
    if (Y >= Hp) return;

    float* xw = lds;                    // 3 private x-row buffers
    float* mb = lds + NBUF * BROW;      // mask rows [2][BROW]

    // ---- prologue (wave-private; NO barriers anywhere) ----
    // Mask rows: r=0 -> row Y, r=1 -> row Y-1 (guard-padded; OOB -> zeros).
#pragma unroll
    for (int r = 0; r < 2; ++r) {
        int g = Y - r;
        float* mrow = mb + r * BROW;
        if ((unsigned)g < (unsigned)H) {
            const float* src = mask + (size_t)g * W + lane * 4;
            gl_lds16(src,       mrow + GUARD);
            gl_lds16(src + 256, mrow + GUARD + 256);
            gl_lds16(src + 512, mrow + GUARD + 512);
            gl_lds16(src + 768, mrow + GUARD + 768);
            mrow[lane] = 0.f;
            mrow[GUARD + 1024 + lane] = 0.f;
        } else {
            for (int k = lane; k < BROW; k += 64) mrow[k] = 0.f;
        }
    }
    // Zero x-buf guard columns (read by edge pixels; never staged).
#pragma unroll
    for (int b = 0; b < NBUF; ++b) {
        xw[b * BROW + lane] = 0.f;
        xw[b * BROW + GUARD + 1024 + lane] = 0.f;
    }
    // Stage bands 0,1 (4 x 1KB gl_lds each).
#pragma unroll
    for (int j = 0; j < 2; ++j) {
        int dyj = __shfl(dyi, j, 64);
        int srow = min(max(Y - dyj, 0), H - 1);  // clamp; zero mask row kills OOB
        const float* src = x + (size_t)j * HW + (size_t)srow * W + lane * 4;
        float* dst = xw + j * BROW + GUARD;
        gl_lds16(src, dst);
        gl_lds16(src + 256, dst + 256);
        gl_lds16(src + 512, dst + 512);
        gl_lds16(src + 768, dst + 768);
    }

    // Clamped pixel offsets (band-independent; also LDS bounds-safety).
    int te[NPASS];
#pragma unroll
    for (int p = 0; p < NPASS; ++p) {
        int t = p * 128 + 2 * lane;
        te[p] = (t < Wp) ? t : 0;
    }
    f2 acc[NPASS];
#pragma unroll
    for (int p = 0; p < NPASS; ++p) acc[p] = f2{0.f, 0.f};

    // ---- per-wave counted-vmcnt pipeline over all 28 bands, depth 2 ----
    // vmcnt ledger (outstanding before wait at iter j): mask(8, j=0 only) +
    // bands j..j+2 (12) -> vmcnt(8) guarantees band j + mask landed.
#pragma unroll
    for (int j = 0; j < NL; ++j) {
        if (j + 2 < NL) {  // stage band j+2 into buf (j+2)%3
            int l = j + 2;
            int dyj = __shfl(dyi, l, 64);
            int srow = min(max(Y - dyj, 0), H - 1);
            const float* src = x + (size_t)l * HW + (size_t)srow * W + lane * 4;
            float* dst = xw + ((j + 2) % NBUF) * BROW + GUARD;
            gl_lds16(src, dst);
            gl_lds16(src + 256, dst + 256);
            gl_lds16(src + 512, dst + 512);
            gl_lds16(src + 768, dst + 768);
        }
        if (j + 2 < NL)      asm volatile("s_waitcnt vmcnt(8)" ::: "memory");
        else if (j + 1 < NL) asm volatile("s_waitcnt vmcnt(4)" ::: "memory");
        else                 asm volatile("s_waitcnt vmcnt(0)" ::: "memory");

        int dxj = __shfl(dxi, j, 64);
        int dyj = __shfl(dyi, j, 64);
        const float* xb = xw + (j % NBUF) * BROW + GUARD - dxj;
        const float* mrow = mb + dyj * BROW + GUARD - dxj;
#pragma unroll
        for (int p = 0; p < NPASS; ++p) {
            f2 xv = *(const f2*)&xb[te[p]];     // ds_read2_b32
            f2 mv = *(const f2*)&mrow[te[p]];   // ds_read2_b32
            acc[p] += xv * mv;
        }
        // Own ds_reads of buf j%3 must complete before iter j+1's stage
        // (target (j+3)%3 == j%3) overwrites it. Wave-local, ~free (reads
        // already consumed by the FMAs above).
        asm volatile("s_waitcnt lgkmcnt(0)" ::: "memory");
        __builtin_amdgcn_sched_barrier(0);
    }

    // ---- store row directly (no reduction: this wave owns all bands) ----
    float* orow = out + (size_t)Y * Wp;
#pragma unroll
    for (int p = 0; p < NPASS; ++p) {
        int t = p * 128 + 2 * lane;
        if (t + 1 < Wp)  *(f2*)&orow[t] = acc[p];
        else if (t < Wp) orow[t] = acc[p].x;
    }
}

extern "C" void kernel_launch(void* const* d_in, const int* in_sizes, int n_in,
                              void* d_out, int out_size, void* d_ws, size_t ws_size,
                              hipStream_t stream) {
    const float* x = (const float*)d_in[0];      // [1, 28, 1024, 1024]
    const float* mask = (const float*)d_in[1];   // [1024, 1024]
    const float* phi = (const float*)d_in[2];    // [1]
    const float* s_nom = (const float*)d_in[3];  // [28]
    float* out = (float*)d_out;                  // [1, Hp, Wp]

    // One 64-thread block per output row; Hp <= out_size/W (since Wp >= W).
    const int blocks = out_size / W + 2;
    cassi_v14<<<blocks, 64, 0, stream>>>(x, mask, phi, s_nom, out, out_size);
}

// Round 15
// 27.143 us; speedup vs baseline: 3.7520x; 3.7520x over previous
//
#include <hip/hip_runtime.h>
#include <math.h>

#define NL 28
#define H 1024
#define W 1024
#define HW (H * W)
#define BROW 1152         // padded row: 64 guard | 1024 data | 64 guard
#define GUARD 64
#define NWAVE 2           // waves per block
#define WBANDS 14         // bands per wave (2 x 14 = 28)
#define NBUF 3            // per-wave x buffers (depth-2 prefetch)
#define WREG (NBUF * BROW)  // per-wave LDS floats (3456)
#define NPASS 9           // 9 x 128 px passes cover Wp <= 1152

// 8B vector, 4B-alignment-safe -> ds_read2_b32.
typedef float f2 __attribute__((ext_vector_type(2), aligned(4)));

typedef __attribute__((address_space(1))) const void GV;
typedef __attribute__((address_space(3))) void LV;
__device__ __forceinline__ void gl_lds16(const float* g, float* l) {
    __builtin_amdgcn_global_load_lds((GV*)g, (LV*)l, 16, 0, 0);
}

// out[Y,X] = sum_l mask[Y-dy_l, X-dx_l] * x[l, Y-dy_l, X-dx_l]
// One block per output row; BARRIER-FREE per-wave band pipelines.
// v15 == v12 verbatim (proven 27.0 us): 2 waves x 14 bands, 3 private
// buffers each, depth-2 counted-vmcnt pipeline, 36 KB LDS -> 4 blocks/CU.
// v13 (XCD swizzle + split epilogue + dropped lgkm drain) regressed to 28.4;
// v14 (1 wave x 28 bands) spilled at 256 VGPR -> 102 us. 14 bands/wave is
// the regalloc-safe pipeline depth; restore and hold.
__global__ __launch_bounds__(128, 2)
void cassi_v15(const float* __restrict__ x, const float* __restrict__ mask,
               const float* __restrict__ phi_deg, const float* __restrict__ s_nom,
               float* __restrict__ out, int out_size)
{
    __shared__ float lds[NWAVE * WREG + 2 * BROW];  // 36 KB

    const int tid = threadIdx.x;
    const int lane = tid & 63;
    const int wid = tid >> 6;

    // ---- offsets: computed redundantly by every wave (no broadcast sync) ----
    float phi = phi_deg[0] * 0.017453292519943295f;
    float c = cosf(phi), sn = sinf(phi);
    float s = (lane < NL) ? s_nom[lane] : 0.f;
    float dxv = s * c, dyv = s * sn;
    float dxm = (lane < NL) ? dxv : 3.0e38f;
    float dym = (lane < NL) ? dyv : 3.0e38f;
    for (int d = 1; d < 64; d <<= 1) {
        dxm = fminf(dxm, __shfl_xor(dxm, d, 64));
        dym = fminf(dym, __shfl_xor(dym, d, 64));
    }
    int dxi = (lane < NL) ? (int)rintf(dxv - dxm) : 0;
    int dyi = (lane < NL) ? (int)rintf(dyv - dym) : 0;
    int dxmax = dxi, dymax = dyi;
    for (int d = 1; d < 64; d <<= 1) {
        dxmax = max(dxmax, __shfl_xor(dxmax, d, 64));
        dymax = max(dymax, __shfl_xor(dymax, d, 64));
    }
    const int Wp = W + dxmax;
    const int Hp = out_size / Wp;

    if (!(dymax <= 1 && dxmax <= GUARD)) {
        // Self-contained checked fallback (never taken for bench geometry).
        for (int i = blockIdx.x * 128 + tid; i < out_size; i += gridDim.x * 128) {
            int Yk = i / Wp, Xk = i - Yk * Wp;
            float a = 0.f;
            for (int l = 0; l < NL; ++l) {
                float sl = s_nom[l];
                int dx = (int)rintf(sl * c - dxm);
                int dy = (int)rintf(sl * sn - dym);
                int h = Yk - dy, w = Xk - dx;
                if ((unsigned)h < (unsigned)H && (unsigned)w < (unsigned)W) {
                    int p = h * W + w;
                    a = fmaf(mask[p], x[(size_t)l * HW + p], a);
                }
            }
            out[i] = a;
        }
        return;
    }

    const int Y = blockIdx.x;
    if (Y >= Hp) return;  // uniform exit before any barrier

    float* xw = &lds[wid * WREG];        // this wave's 3 private row buffers
    float* mb = &lds[NWAVE * WREG];      // shared mask rows [2][BROW]

    // Per-band constants in statically-indexed register arrays.
    int xo_[WBANDS], mo_[WBANDS], sr_[WBANDS];
#pragma unroll
    for (int j = 0; j < WBANDS; ++j) {
        int l = wid * WBANDS + j;
        int dxj = __shfl(dxi, l, 64);
        int dyj = __shfl(dyi, l, 64);
        xo_[j] = (j % NBUF) * BROW + GUARD - dxj;
        mo_[j] = dyj * BROW + GUARD - dxj;
        sr_[j] = min(max(Y - dyj, 0), H - 1);  // clamp; zero mask row kills OOB
    }

    // Zero own xbuf guard columns (read by edge pixels; never staged).
#pragma unroll
    for (int b = 0; b < NBUF; ++b) {
        xw[b * BROW + lane] = 0.f;
        xw[b * BROW + GUARD + 1024 + lane] = 0.f;
    }
    // Mask rows: wave 0 -> row Y, wave 1 -> row Y-1 (guard-padded; OOB -> zeros).
    {
        int g = Y - wid;
        float* mrow = &mb[wid * BROW];
        if ((unsigned)g < (unsigned)H) {
            const float* src = mask + (size_t)g * W + lane * 4;
            gl_lds16(src,       mrow + GUARD);
            gl_lds16(src + 256, mrow + GUARD + 256);
            gl_lds16(src + 512, mrow + GUARD + 512);
            gl_lds16(src + 768, mrow + GUARD + 768);
            mrow[lane] = 0.f;
            mrow[GUARD + 1024 + lane] = 0.f;
        } else {
            for (int k = lane; k < BROW; k += 64) mrow[k] = 0.f;
        }
    }
    // Stage own bands 0,1 (4 x 1KB gl_lds each).
#pragma unroll
    for (int j = 0; j < 2; ++j) {
        int l = wid * WBANDS + j;
        const float* src = x + (size_t)l * HW + (size_t)sr_[j] * W + lane * 4;
        float* dst = xw + j * BROW + GUARD;
        gl_lds16(src, dst);
        gl_lds16(src + 256, dst + 256);
        gl_lds16(src + 512, dst + 512);
        gl_lds16(src + 768, dst + 768);
    }
    // vmcnt(8): drains exactly the 4 mask loads (own bands 0,1 stay in
    // flight); lgkmcnt(0) publishes guard ds_writes.
    asm volatile("s_waitcnt vmcnt(8) lgkmcnt(0)" ::: "memory");
    __builtin_amdgcn_s_barrier();   // the ONLY pre-loop barrier (mask ready)

    // Clamped pixel offsets (band-independent). Clamp keeps mo_+te within the
    // mb region (right guard absorbs the tail) -- also bounds-safety.
    int te[NPASS];
#pragma unroll
    for (int p = 0; p < NPASS; ++p) {
        int t = p * 128 + 2 * lane;
        te[p] = (t < Wp) ? t : 0;
    }

    f2 acc[NPASS];
#pragma unroll
    for (int p = 0; p < NPASS; ++p) acc[p] = f2{0.f, 0.f};

    // ---- barrier-free per-wave pipeline over 14 bands, depth 2 ----
#pragma unroll
    for (int j = 0; j < WBANDS; ++j) {
        if (j + 2 < WBANDS) {  // stage band j+2 into private buf (j+2)%3
            int l = wid * WBANDS + j + 2;
            const float* src = x + (size_t)l * HW + (size_t)sr_[j + 2] * W + lane * 4;
            float* dst = xw + ((j + 2) % NBUF) * BROW + GUARD;
            gl_lds16(src, dst);
            gl_lds16(src + 256, dst + 256);
            gl_lds16(src + 512, dst + 512);
            gl_lds16(src + 768, dst + 768);
        }
        // Counted per-wave wait: band j landed; deeper prefetch in flight.
        if (j + 2 < WBANDS)      asm volatile("s_waitcnt vmcnt(8)" ::: "memory");
        else if (j + 1 < WBANDS) asm volatile("s_waitcnt vmcnt(4)" ::: "memory");
        else                     asm volatile("s_waitcnt vmcnt(0)" ::: "memory");

        const float* xb = xw + xo_[j];
        const float* mrow = mb + mo_[j];
#pragma unroll
        for (int p = 0; p < NPASS; ++p) {
            f2 xv = *(const f2*)&xb[te[p]];     // ds_read2_b32
            f2 mv = *(const f2*)&mrow[te[p]];   // ds_read2_b32
            acc[p] += xv * mv;
        }
        // Own ds_reads of buf j%3 must finish before iter j+1 overwrites it
        // (stage target (j+3)%3 == j%3). Wave-local, cheap.
        asm volatile("s_waitcnt lgkmcnt(0)" ::: "memory");
        __builtin_amdgcn_sched_barrier(0);
    }

    // ---- partials -> own region start (bands done; private to this wave) ----
#pragma unroll
    for (int p = 0; p < NPASS; ++p) {
        int t = p * 128 + 2 * lane;
        *(f2*)&xw[t] = acc[p];   // t <= 1150 < WREG, always in-bounds
    }
    asm volatile("s_waitcnt lgkmcnt(0)" ::: "memory");
    __builtin_amdgcn_s_barrier();   // partials visible

    // ---- 2-way reduce + store ----
    float* orow = out + (size_t)Y * Wp;
#pragma unroll
    for (int q = 0; q < 5; ++q) {
        int t = 2 * (tid + q * 128);
        if (t + 1 < Wp) {
            f2 v = *(const f2*)&lds[t];
            v += *(const f2*)&lds[WREG + t];
            *(f2*)&orow[t] = v;
        } else if (t < Wp) {
            orow[t] = lds[t] + lds[WREG + t];
        }
    }
}

extern "C" void kernel_launch(void* const* d_in, const int* in_sizes, int n_in,
                              void* d_out, int out_size, void* d_ws, size_t ws_size,
                              hipStream_t stream) {
    const float* x = (const float*)d_in[0];      // [1, 28, 1024, 1024]
    const float* mask = (const float*)d_in[1];   // [1024, 1024]
    const float* phi = (const float*)d_in[2];    // [1]
    const float* s_nom = (const float*)d_in[3];  // [28]
    float* out = (float*)d_out;                  // [1, Hp, Wp]

    // One block per output row; Hp <= out_size/W (since Wp >= W).
    const int blocks = out_size / W + 2;
    cassi_v15<<<blocks, 128, 0, stream>>>(x, mask, phi, s_nom, out, out_size);
}

// Round 16
// 26.198 us; speedup vs baseline: 3.8873x; 1.0361x over previous
//
#include <hip/hip_runtime.h>
#include <math.h>

#define NL 28
#define H 1024
#define W 1024
#define HW (H * W)
#define BROW 1152         // padded row: 64 guard | 1024 data | 64 guard
#define GUARD 64
#define NWAVE 2           // waves per block
#define WBANDS 14         // bands per wave (2 x 14 = 28)
#define NBUF 3            // per-wave x buffers (depth-2 prefetch)
#define WREG (NBUF * BROW)  // per-wave LDS floats (3456)
#define NPASS 9           // 9 x 128 px passes cover Wp <= 1152

// Naturally-aligned 8B vector -> backend emits ds_read_b64 / ds_write_b64
// (vs v15's aligned(4) f2 -> ds_read2_b32, 2 internal dword ops, ~2x LDS
// pipe cost). SAFE only because the fast path is gated on "all dx even"
// (every f2 address is then base+even_float = 8B aligned); odd-dx inputs
// take the checked fallback.
typedef float f2 __attribute__((ext_vector_type(2)));

typedef __attribute__((address_space(1))) const void GV;
typedef __attribute__((address_space(3))) void LV;
__device__ __forceinline__ void gl_lds16(const float* g, float* l) {
    __builtin_amdgcn_global_load_lds((GV*)g, (LV*)l, 16, 0, 0);
}

// out[Y,X] = sum_l mask[Y-dy_l, X-dx_l] * x[l, Y-dy_l, X-dx_l]
// One block per output row; barrier-free per-wave band pipelines (v12/v15
// structure, proven 27.0us). v16: single change = 8B-aligned LDS vector ops.
__global__ __launch_bounds__(128, 2)
void cassi_v16(const float* __restrict__ x, const float* __restrict__ mask,
               const float* __restrict__ phi_deg, const float* __restrict__ s_nom,
               float* __restrict__ out, int out_size)
{
    __shared__ float lds[NWAVE * WREG + 2 * BROW];  // 36 KB

    const int tid = threadIdx.x;
    const int lane = tid & 63;
    const int wid = tid >> 6;

    // ---- offsets: computed redundantly by every wave (no broadcast sync) ----
    float phi = phi_deg[0] * 0.017453292519943295f;
    float c = cosf(phi), sn = sinf(phi);
    float s = (lane < NL) ? s_nom[lane] : 0.f;
    float dxv = s * c, dyv = s * sn;
    float dxm = (lane < NL) ? dxv : 3.0e38f;
    float dym = (lane < NL) ? dyv : 3.0e38f;
    for (int d = 1; d < 64; d <<= 1) {
        dxm = fminf(dxm, __shfl_xor(dxm, d, 64));
        dym = fminf(dym, __shfl_xor(dym, d, 64));
    }
    int dxi = (lane < NL) ? (int)rintf(dxv - dxm) : 0;
    int dyi = (lane < NL) ? (int)rintf(dyv - dym) : 0;
    int dxmax = dxi, dymax = dyi, dxodd = dxi & 1;
    for (int d = 1; d < 64; d <<= 1) {
        dxmax = max(dxmax, __shfl_xor(dxmax, d, 64));
        dymax = max(dymax, __shfl_xor(dymax, d, 64));
        dxodd = max(dxodd, __shfl_xor(dxodd, d, 64));  // OR: any odd dx?
    }
    const int Wp = W + dxmax;
    const int Hp = out_size / Wp;

    // Fast path requires: small dy, dx within guard, and ALL dx even
    // (8B alignment proof for the b64 LDS ops below).
    if (!(dymax <= 1 && dxmax <= GUARD && dxodd == 0)) {
        // Self-contained checked fallback (never taken for bench geometry).
        for (int i = blockIdx.x * 128 + tid; i < out_size; i += gridDim.x * 128) {
            int Yk = i / Wp, Xk = i - Yk * Wp;
            float a = 0.f;
            for (int l = 0; l < NL; ++l) {
                float sl = s_nom[l];
                int dx = (int)rintf(sl * c - dxm);
                int dy = (int)rintf(sl * sn - dym);
                int h = Yk - dy, w = Xk - dx;
                if ((unsigned)h < (unsigned)H && (unsigned)w < (unsigned)W) {
                    int p = h * W + w;
                    a = fmaf(mask[p], x[(size_t)l * HW + p], a);
                }
            }
            out[i] = a;
        }
        return;
    }

    const int Y = blockIdx.x;
    if (Y >= Hp) return;  // uniform exit before any barrier

    float* xw = &lds[wid * WREG];        // this wave's 3 private row buffers
    float* mb = &lds[NWAVE * WREG];      // shared mask rows [2][BROW]

    // Per-band constants in statically-indexed register arrays.
    // All even (BROW, GUARD even; dx even by gate) -> 8B-aligned f2 bases.
    int xo_[WBANDS], mo_[WBANDS], sr_[WBANDS];
#pragma unroll
    for (int j = 0; j < WBANDS; ++j) {
        int l = wid * WBANDS + j;
        int dxj = __shfl(dxi, l, 64);
        int dyj = __shfl(dyi, l, 64);
        xo_[j] = (j % NBUF) * BROW + GUARD - dxj;
        mo_[j] = dyj * BROW + GUARD - dxj;
        sr_[j] = min(max(Y - dyj, 0), H - 1);  // clamp; zero mask row kills OOB
    }

    // Zero own xbuf guard columns (read by edge pixels; never staged).
#pragma unroll
    for (int b = 0; b < NBUF; ++b) {
        xw[b * BROW + lane] = 0.f;
        xw[b * BROW + GUARD + 1024 + lane] = 0.f;
    }
    // Mask rows: wave 0 -> row Y, wave 1 -> row Y-1 (guard-padded; OOB -> zeros).
    {
        int g = Y - wid;
        float* mrow = &mb[wid * BROW];
        if ((unsigned)g < (unsigned)H) {
            const float* src = mask + (size_t)g * W + lane * 4;
            gl_lds16(src,       mrow + GUARD);
            gl_lds16(src + 256, mrow + GUARD + 256);
            gl_lds16(src + 512, mrow + GUARD + 512);
            gl_lds16(src + 768, mrow + GUARD + 768);
            mrow[lane] = 0.f;
            mrow[GUARD + 1024 + lane] = 0.f;
        } else {
            for (int k = lane; k < BROW; k += 64) mrow[k] = 0.f;
        }
    }
    // Stage own bands 0,1 (4 x 1KB gl_lds each).
#pragma unroll
    for (int j = 0; j < 2; ++j) {
        int l = wid * WBANDS + j;
        const float* src = x + (size_t)l * HW + (size_t)sr_[j] * W + lane * 4;
        float* dst = xw + j * BROW + GUARD;
        gl_lds16(src, dst);
        gl_lds16(src + 256, dst + 256);
        gl_lds16(src + 512, dst + 512);
        gl_lds16(src + 768, dst + 768);
    }
    // vmcnt(8): drains exactly the 4 mask loads (own bands 0,1 stay in
    // flight); lgkmcnt(0) publishes guard ds_writes.
    asm volatile("s_waitcnt vmcnt(8) lgkmcnt(0)" ::: "memory");
    __builtin_amdgcn_s_barrier();   // the ONLY pre-loop barrier (mask ready)

    // Clamped pixel offsets (band-independent; even -> preserves alignment).
    int te[NPASS];
#pragma unroll
    for (int p = 0; p < NPASS; ++p) {
        int t = p * 128 + 2 * lane;
        te[p] = (t < Wp) ? t : 0;
    }

    f2 acc[NPASS];
#pragma unroll
    for (int p = 0; p < NPASS; ++p) acc[p] = f2{0.f, 0.f};

    // ---- barrier-free per-wave pipeline over 14 bands, depth 2 ----
#pragma unroll
    for (int j = 0; j < WBANDS; ++j) {
        if (j + 2 < WBANDS) {  // stage band j+2 into private buf (j+2)%3
            int l = wid * WBANDS + j + 2;
            const float* src = x + (size_t)l * HW + (size_t)sr_[j + 2] * W + lane * 4;
            float* dst = xw + ((j + 2) % NBUF) * BROW + GUARD;
            gl_lds16(src, dst);
            gl_lds16(src + 256, dst + 256);
            gl_lds16(src + 512, dst + 512);
            gl_lds16(src + 768, dst + 768);
        }
        // Counted per-wave wait: band j landed; deeper prefetch in flight.
        if (j + 2 < WBANDS)      asm volatile("s_waitcnt vmcnt(8)" ::: "memory");
        else if (j + 1 < WBANDS) asm volatile("s_waitcnt vmcnt(4)" ::: "memory");
        else                     asm volatile("s_waitcnt vmcnt(0)" ::: "memory");

        const float* xb = xw + xo_[j];
        const float* mrow = mb + mo_[j];
#pragma unroll
        for (int p = 0; p < NPASS; ++p) {
            f2 xv = *(const f2*)&xb[te[p]];     // ds_read_b64 (8B aligned)
            f2 mv = *(const f2*)&mrow[te[p]];   // ds_read_b64
            acc[p] += xv * mv;
        }
        // Own ds_reads of buf j%3 must finish before iter j+1 overwrites it
        // (stage target (j+3)%3 == j%3). Wave-local, cheap.
        asm volatile("s_waitcnt lgkmcnt(0)" ::: "memory");
        __builtin_amdgcn_sched_barrier(0);
    }

    // ---- partials -> own region start (bands done; private to this wave) ----
#pragma unroll
    for (int p = 0; p < NPASS; ++p) {
        int t = p * 128 + 2 * lane;
        *(f2*)&xw[t] = acc[p];   // ds_write_b64; t <= 1150 < WREG
    }
    asm volatile("s_waitcnt lgkmcnt(0)" ::: "memory");
    __builtin_amdgcn_s_barrier();   // partials visible

    // ---- 2-way reduce + store ----
    float* orow = out + (size_t)Y * Wp;   // Wp even -> rows stay 8B aligned
#pragma unroll
    for (int q = 0; q < 5; ++q) {
        int t = 2 * (tid + q * 128);
        if (t + 1 < Wp) {
            f2 v = *(const f2*)&lds[t];
            v += *(const f2*)&lds[WREG + t];
            *(f2*)&orow[t] = v;
        } else if (t < Wp) {
            orow[t] = lds[t] + lds[WREG + t];
        }
    }
}

extern "C" void kernel_launch(void* const* d_in, const int* in_sizes, int n_in,
                              void* d_out, int out_size, void* d_ws, size_t ws_size,
                              hipStream_t stream) {
    const float* x = (const float*)d_in[0];      // [1, 28, 1024, 1024]
    const float* mask = (const float*)d_in[1];   // [1024, 1024]
    const float* phi = (const float*)d_in[2];    // [1]
    const float* s_nom = (const float*)d_in[3];  // [28]
    float* out = (float*)d_out;                  // [1, Hp, Wp]

    // One block per output row; Hp <= out_size/W (since Wp >= W).
    const int blocks = out_size / W + 2;
    cassi_v16<<<blocks, 128, 0, stream>>>(x, mask, phi, s_nom, out, out_size);
}